// Round 1
// 24.138 us; speedup vs baseline: 1.3484x; 1.3484x over previous
//
#include <hip/hip_runtime.h>
#include <hip/hip_bf16.h>
#include <math.h>

#define IN_DIM   512
#define OUT_DIM  512
#define NK       192          // TOTAL_K
#define KF       384          // 2*TOTAL_K
#define XAVIER   0.04419417382415922f
#define BIAS_SCALE 0.02f

typedef __attribute__((ext_vector_type(8))) short bf16x8;
typedef __attribute__((ext_vector_type(4))) float f32x4;
typedef unsigned short u16;
typedef unsigned int   u32;
typedef unsigned long long u64;

__device__ inline u16 f2bf(float f) {
    __hip_bfloat16 h = __float2bfloat16(f);
    return *reinterpret_cast<u16*>(&h);
}
__device__ inline u32 pack2bf(float lo, float hi) {
    return (u32)f2bf(lo) | ((u32)f2bf(hi) << 16);
}
__device__ inline void gload_lds16(const void* g, void* l) {
    __builtin_amdgcn_global_load_lds(
        (const __attribute__((address_space(1))) void*)g,
        (__attribute__((address_space(3))) void*)l, 16, 0, 0);
}
// Native-rate sincos: v_sin/v_cos take revolutions. |arg| < ~50 rad here, so
// fract-reduction is exact enough (err ~1e-6 << bf16-W quantization ~4e-3 rel).
__device__ inline void fsincos(float x, float& s, float& c) {
    float t = x * 0.15915494309189535f;   // 1/(2*pi)
    t -= floorf(t);
    s = __builtin_amdgcn_sinf(t);
    c = __builtin_amdgcn_cosf(t);
}

// ---------------------------------------------------------------------------
// Kernel 1: 256 blocks x 512 threads.
//  - all 512 threads fill the U/V angle-addition tables (12 iters) [native sincos]
//  - waves 4..7 compute this block's 2 bias outputs k-parallel (depth ~2, was 192)
//  - waves 0..3 run the 32x32x384 MFMA tile GEMM -> Wt
// ---------------------------------------------------------------------------
__global__ __launch_bounds__(512) void synth_fused(
    const float* __restrict__ omega, const float* __restrict__ phi,
    const float* __restrict__ alpha, const float* __restrict__ alpha_bias,
    const int* __restrict__ layer_idx, const int* __restrict__ num_layers,
    u16* __restrict__ Wt, float* __restrict__ bias)
{
    const int b   = blockIdx.x;
    const int tid = threadIdx.x;
    const float l = ((float)layer_idx[0] + 1.0f) / ((float)num_layers[0] + 1.0f);

    __shared__ u16 sV[32 * KF];   // 24KB, row j_local, swizzled rows of 768B
    __shared__ u16 sU[32 * KF];   // 24KB, row i_local, swizzled
    __shared__ float bsc[4];

    const int bi = b & 15, bj = b >> 4;
    const int i0 = bi * 32, j0 = bj * 32;

    // ---- fill: 32 rows x 192 k over 512 threads = 12 iters ----
    #pragma unroll 4
    for (int q = 0; q < 12; ++q) {
        const int e  = q * 512 + tid;     // 0..6143
        const int rl = e / NK;
        const int k  = e - rl * NK;
        const int swz  = (rl & 7) << 4;
        const int base = rl * (KF * 2);   // row byte base
        const float om0 = omega[3*k], om1 = omega[3*k+1], om2 = omega[3*k+2];
        const float ph  = phi[k];
        {
            const float ii = (i0 + rl + 1.0f) * (1.0f / (IN_DIM + 1.0f));
            float s, c; fsincos(fmaf(ii, om0, fmaf(l, om2, ph)), s, c);
            *(u16*)((char*)sU + base + (((2*k)      ) ^ swz)) = f2bf(s);
            *(u16*)((char*)sU + base + (((2*k) + 384) ^ swz)) = f2bf(c);
        }
        {
            const float jj = (j0 + rl + 1.0f) * (1.0f / (OUT_DIM + 1.0f));
            float sv, cv; fsincos(jj * om1, sv, cv);
            const float as = alpha[k], ac = alpha[NK + k];
            *(u16*)((char*)sV + base + (((2*k)      ) ^ swz)) = f2bf((as*cv - ac*sv) * XAVIER);
            *(u16*)((char*)sV + base + (((2*k) + 384) ^ swz)) = f2bf((ac*cv + as*sv) * XAVIER);
        }
    }

    // ---- bias partials: waves 4..7; block b owns outputs 2b, 2b+1 ----
    if (tid >= 256) {
        const int t2 = tid - 256;         // 0..255
        const int g  = t2 >> 7;           // 0,1 -> which j
        const int k0 = t2 & 127;
        const int j  = 2*b + g;
        const float jj = (j + 1.0f) * (1.0f / (OUT_DIM + 1.0f));
        float bp = 0.0f;
        {
            float s, c;
            fsincos(fmaf(jj, omega[3*k0+1], fmaf(l, omega[3*k0+2], phi[k0])), s, c);
            bp = fmaf(alpha_bias[k0], s, fmaf(alpha_bias[NK + k0], c, bp));
        }
        if (k0 < 64) {
            const int k = k0 + 128;
            float s, c;
            fsincos(fmaf(jj, omega[3*k+1], fmaf(l, omega[3*k+2], phi[k])), s, c);
            bp = fmaf(alpha_bias[k], s, fmaf(alpha_bias[NK + k], c, bp));
        }
        #pragma unroll
        for (int off = 32; off > 0; off >>= 1)
            bp += __shfl_down(bp, off);
        if ((tid & 63) == 0) bsc[t2 >> 6] = bp;   // waves 4..7 -> 0..3
    }
    __syncthreads();

    // ---- 32x32x384 GEMM (waves 0..3): Wt[j][i] = sum_k V[j][k]*U[i][k] ----
    if (tid < 256) {
        const int wave = tid >> 6, lane = tid & 63;
        const int wr = wave >> 1, wc = wave & 1;
        f32x4 acc = {};
        #pragma unroll
        for (int kk = 0; kk < KF / 32; ++kk) {
            const int kb = kk * 64 + (lane >> 4) * 16;
            const int ra = wr*16 + (lane & 15);
            const int rb = wc*16 + (lane & 15);
            bf16x8 a = *reinterpret_cast<const bf16x8*>(
                (const char*)sV + ra*768 + (kb ^ ((ra & 7) << 4)));
            bf16x8 bb = *reinterpret_cast<const bf16x8*>(
                (const char*)sU + rb*768 + (kb ^ ((rb & 7) << 4)));
            acc = __builtin_amdgcn_mfma_f32_16x16x32_bf16(a, bb, acc, 0, 0, 0);
        }
        const int row = j0 + wr*16 + (lane >> 4) * 4;   // out col j
        const int col = i0 + wc*16 + (lane & 15);       // in row i
        #pragma unroll
        for (int r = 0; r < 4; ++r)
            Wt[(size_t)(row + r) * IN_DIM + col] = f2bf(acc[r]);
    }
    if (tid == 256) bias[2*b    ] = (bsc[0] + bsc[1]) * BIAS_SCALE;
    if (tid == 257) bias[2*b + 1] = (bsc[2] + bsc[3]) * BIAS_SCALE;
}

// ---------------------------------------------------------------------------
// Kernel 2: out (M x 512) = x @ W + b.  Same layouts/swizzles as before, but
// the per-step __syncthreads() vmcnt(0) drain is replaced by a counted-vmcnt
// 2-barrier pipeline: stage(t+2) is issued after the compute-done barrier and
// s_waitcnt vmcnt(8) retires exactly B(t+1)+A(t+2), leaving the 8 newest B
// loads in flight across both barriers (T3/T4 discipline).
// ---------------------------------------------------------------------------
__global__ __launch_bounds__(512) void main_gemm(
    const float* __restrict__ X, const u16* __restrict__ Wt,
    const float* __restrict__ bias, float* __restrict__ out, int M)
{
    __shared__ u16 sA[2][32 * 64];    // 2 x 4KB
    __shared__ u16 sB[2][512 * 64];   // 2 x 64KB

    const int tid  = threadIdx.x;
    const int w    = tid >> 6, lane = tid & 63;
    const int brow = blockIdx.x * 32;

    f32x4 acc[2][4] = {};

    const int bsrc  = ((lane & 7) * 16) ^ ((lane >> 3) << 4);
    const int bjrow = lane >> 3;
    const int arow = tid >> 4;
    const int akq  = tid & 15;
    const int adst = arow * 128 + (((akq * 8)) ^ ((arow & 7) << 4));
    const size_t xoff = (size_t)(brow + arow) * IN_DIM + akq * 4;

    auto stageB = [&](int buf, int k0) {
        #pragma unroll
        for (int c = 0; c < 8; ++c) {
            const int ci = w * 8 + c;
            const int j  = ci * 8 + bjrow;
            gload_lds16((const char*)Wt + (size_t)j * (IN_DIM * 2) + k0 * 2 + bsrc,
                        (char*)&sB[buf][0] + ci * 1024);
        }
    };
    auto loadA = [&](int k0) -> f32x4 {
        return *reinterpret_cast<const f32x4*>(&X[xoff + k0]);
    };
    auto writeA = [&](int buf, f32x4 v) {
        u64 p = (u64)pack2bf(v.x, v.y) | ((u64)pack2bf(v.z, v.w) << 32);
        *reinterpret_cast<u64*>((char*)&sA[buf][0] + adst) = p;
    };
    auto compute = [&](int buf) {
        #pragma unroll
        for (int kk = 0; kk < 2; ++kk) {
            const int kb = kk * 64 + (lane >> 4) * 16;
            bf16x8 a[2], bb[4];
            #pragma unroll
            for (int m = 0; m < 2; ++m) {
                const int r = m*16 + (lane & 15);
                a[m] = *reinterpret_cast<const bf16x8*>(
                    (const char*)&sA[buf][0] + r*128 + (kb ^ ((r & 7) << 4)));
            }
            #pragma unroll
            for (int n = 0; n < 4; ++n) {
                const int j = w*64 + n*16 + (lane & 15);
                bb[n] = *reinterpret_cast<const bf16x8*>(
                    (const char*)&sB[buf][0] + j*128 + (kb ^ ((j & 7) << 4)));
            }
            #pragma unroll
            for (int m = 0; m < 2; ++m)
                #pragma unroll
                for (int n = 0; n < 4; ++n)
                    acc[m][n] = __builtin_amdgcn_mfma_f32_16x16x32_bf16(
                        a[m], bb[n], acc[m][n], 0, 0, 0);
        }
    };

    #define VMW(n)  asm volatile("s_waitcnt vmcnt(" #n ")" ::: "memory")
    #define LGKM0   asm volatile("s_waitcnt lgkmcnt(0)" ::: "memory")
    #define BARRIER do { __builtin_amdgcn_s_barrier(); \
                         asm volatile("" ::: "memory"); } while (0)

    // prologue: stage steps 0 and 1 --------------------------------------
    {
        f32x4 av = loadA(0);
        stageB(0, 0);
        VMW(8);               // av(0) ready (8 B(0) still in flight)
        writeA(0, av);
        av = loadA(64);
        stageB(1, 64);
        VMW(8);               // retires B(0) fully + av(1); B(1) in flight
        writeA(1, av);
        LGKM0;                // my ds_writes committed
        BARRIER;              // B(0)+A(0)+A(1) published to all waves
    }

    // main loop: per-wave outstanding VMEM = 8 B(t+1) [+ 1 A(t+2) + 8 B(t+2)]
    #pragma unroll
    for (int t = 0; t < 8; ++t) {
        compute(t & 1);       // B(t),A(t) guaranteed by barrier at end of t-1
        BARRIER;              // everyone done reading buf[t&1] -> safe to overwrite
        if (t < 6) {
            f32x4 av = loadA((t + 2) * 64);
            stageB(t & 1, (t + 2) * 64);
            VMW(8);           // retires B(t+1) + av(t+2); keeps 8 B(t+2) in flight
            writeA(t & 1, av);
        } else if (t == 6) {
            VMW(0);           // last buffer: drain B(7)
        }
        LGKM0;                // my ds_write visible before barrier
        BARRIER;              // publish B(t+1) (+ A(t+2)) to all waves
    }

    #undef VMW
    #undef LGKM0
    #undef BARRIER

    // epilogue ------------------------------------------------------------
    #pragma unroll
    for (int n = 0; n < 4; ++n) {
        const int col = w*64 + n*16 + (lane & 15);
        const float bv = bias[col];
        #pragma unroll
        for (int m = 0; m < 2; ++m) {
            const int row0 = brow + m*16 + (lane >> 4) * 4;
            #pragma unroll
            for (int r = 0; r < 4; ++r)
                out[(size_t)(row0 + r) * OUT_DIM + col] = acc[m][n][r] + bv;
        }
    }
}

// ---------------------------------------------------------------------------
extern "C" void kernel_launch(void* const* d_in, const int* in_sizes, int n_in,
                              void* d_out, int out_size, void* d_ws, size_t ws_size,
                              hipStream_t stream) {
    const float* x          = (const float*)d_in[0];
    const float* omega      = (const float*)d_in[1];
    const float* phi        = (const float*)d_in[2];
    const float* alpha      = (const float*)d_in[3];
    const float* alpha_bias = (const float*)d_in[4];
    const int*   layer_idx  = (const int*)d_in[5];
    const int*   num_layers = (const int*)d_in[6];
    float* out = (float*)d_out;

    const int M = in_sizes[0] / IN_DIM;   // 8192

    u16*   Wt   = (u16*)d_ws;                                  // 512KB
    float* bias = (float*)((char*)d_ws + 512 * 1024);          // 2KB

    synth_fused<<<256, 512, 0, stream>>>(omega, phi, alpha, alpha_bias,
                                         layer_idx, num_layers, Wt, bias);
    main_gemm<<<M / 32, 512, 0, stream>>>(x, Wt, bias, out, M);
}